// Round 1
// baseline (415.012 us; speedup 1.0000x reference)
//
#include <hip/hip_runtime.h>

typedef __bf16 bf16x8 __attribute__((ext_vector_type(8)));
typedef float f32x4 __attribute__((ext_vector_type(4)));
typedef unsigned short u16x8 __attribute__((ext_vector_type(8)));

typedef const void __attribute__((address_space(1)))* gas_ptr;
typedef void __attribute__((address_space(3)))* las_ptr;

#define GLOAD16(gp, lp) __builtin_amdgcn_global_load_lds((gas_ptr)(gp), (las_ptr)(lp), 16, 0, 0)

__device__ __forceinline__ unsigned short f2bf(float f) {
  unsigned int u = __float_as_uint(f);
  u += 0x7FFF + ((u >> 16) & 1);
  return (unsigned short)(u >> 16);
}

// ---------------- prep: W2 [512][4000] f32 -> W2T [4096][512] bf16 (zero-padded) ----------------
__global__ __launch_bounds__(256) void k_w2t(const float* __restrict__ W2,
                                             unsigned short* __restrict__ W2T) {
  __shared__ float tile[64][65];
  const int gt = blockIdx.x;   // 64 tiles of 64 genes (4096)
  const int jt = blockIdx.y;   // 8 tiles of 64 j
  const int t = threadIdx.x;
  const int c = t & 63, r4 = t >> 6;
#pragma unroll
  for (int r = 0; r < 16; ++r) {
    int jj = r * 4 + r4;
    int g = gt * 64 + c;
    tile[jj][c] = (g < 4000) ? W2[(size_t)(jt * 64 + jj) * 4000 + g] : 0.f;
  }
  __syncthreads();
#pragma unroll
  for (int r = 0; r < 16; ++r) {
    int gg = r * 4 + r4;
    W2T[(size_t)(gt * 64 + gg) * 512 + jt * 64 + c] = f2bf(tile[c][gg]);
  }
}

// ---------------- prep: mask + masked-b1 row ----------------
__global__ __launch_bounds__(256) void k_mask(const float* __restrict__ z,
                                              const float* __restrict__ W1,
                                              const float* __restrict__ b1,
                                              unsigned char* __restrict__ maskb,
                                              unsigned short* __restrict__ rowb1) {
  __shared__ float zs[32];
  const int b = blockIdx.x, t = threadIdx.x;
  if (t < 32) zs[t] = z[b * 32 + t];
  __syncthreads();
#pragma unroll
  for (int jj = 0; jj < 2; ++jj) {
    int j = t + jj * 256;
    float a = b1[j];
#pragma unroll
    for (int i = 0; i < 32; ++i) a = fmaf(zs[i], W1[i * 512 + j], a);
    bool m = a > 0.f;
    maskb[b * 512 + j] = m ? 1 : 0;
    rowb1[b * 512 + j] = m ? f2bf(b1[j]) : (unsigned short)0;
  }
}

// ---------------- prep: Abig [256][48][512] bf16: rows0-31 mask*W1, row32 mask*b1, 33-47 zero ----
__global__ __launch_bounds__(256) void k_abig(const float* __restrict__ W1,
                                              const unsigned char* __restrict__ maskb,
                                              const unsigned short* __restrict__ rowb1,
                                              unsigned short* __restrict__ Abig) {
  const int b = blockIdx.x, t = threadIdx.x;
#pragma unroll
  for (int k = 0; k < 12; ++k) {
    int c8 = t + k * 256;      // 0..3071
    int row = c8 >> 6;         // 0..47
    int k8 = (c8 & 63) * 8;    // 0..504
    u16x8 out;
    if (row < 32) {
      unsigned long long m8 = *(const unsigned long long*)(maskb + b * 512 + k8);
      const float* w = W1 + row * 512 + k8;
#pragma unroll
      for (int e = 0; e < 8; ++e)
        out[e] = ((m8 >> (e * 8)) & 0xffULL) ? f2bf(w[e]) : (unsigned short)0;
    } else if (row == 32) {
      out = *(const u16x8*)(rowb1 + b * 512 + k8);
    } else {
#pragma unroll
      for (int e = 0; e < 8; ++e) out[e] = 0;
    }
    *(u16x8*)(Abig + ((size_t)b * 48 + row) * 512 + k8) = out;
  }
}

// ---------------- main fused GEMM + epilogue ----------------
// grid (256 samples, 32 gene-chunks of 128); 256 threads = 4 waves
__global__ __launch_bounds__(256) void k_gemm(const unsigned short* __restrict__ Abig,
                                              const unsigned short* __restrict__ W2T,
                                              const float* __restrict__ z,
                                              const float* __restrict__ b2,
                                              const float* __restrict__ log_theta,
                                              float* __restrict__ Gram) {
  __shared__ __align__(16) char smem[45056 + 128];
  char* AbufB = smem;               // 2 * 6144  (A tile 48x64 bf16, swizzled)
  char* BbufB = smem + 12288;       // 2 * 16384 (B tile 128x64 bf16, swizzled)
  float* zs = (float*)(smem + 45056);

  const int b = blockIdx.x;
  const int g0 = blockIdx.y * 128;
  const int t = threadIdx.x;
  const int lane = t & 63;
  const int wave = t >> 6;
  const int l8 = lane >> 3;                       // row-within-8-block
  const int kxor = (((lane & 7) ^ l8) << 3);      // pre-swizzled k element offset
  const int c16 = lane & 15;
  const int lg = lane >> 4;

  f32x4 acc[3][2];
#pragma unroll
  for (int mt = 0; mt < 3; ++mt)
#pragma unroll
    for (int nt = 0; nt < 2; ++nt) acc[mt][nt] = (f32x4){0.f, 0.f, 0.f, 0.f};

  const size_t Abase = (size_t)b * 48 * 512;

#define STAGE(buf, kt)                                                                     \
  do {                                                                                     \
    {                                                                                      \
      int q0 = wave;                                                                       \
      GLOAD16(Abig + Abase + (size_t)(q0 * 8 + l8) * 512 + (kt) * 64 + kxor,               \
              AbufB + (buf) * 6144 + q0 * 1024);                                           \
    }                                                                                      \
    if (wave < 2) {                                                                        \
      int q1 = wave + 4;                                                                   \
      GLOAD16(Abig + Abase + (size_t)(q1 * 8 + l8) * 512 + (kt) * 64 + kxor,               \
              AbufB + (buf) * 6144 + q1 * 1024);                                           \
    }                                                                                      \
    _Pragma("unroll") for (int qq = 0; qq < 4; ++qq) {                                     \
      int q = wave * 4 + qq;                                                               \
      GLOAD16(W2T + (size_t)(g0 + q * 8 + l8) * 512 + (kt) * 64 + kxor,                    \
              BbufB + (buf) * 16384 + q * 1024);                                           \
    }                                                                                      \
  } while (0)

  STAGE(0, 0);
  if (t < 32) zs[t] = z[b * 32 + t];
  __syncthreads();

  for (int kt = 0; kt < 8; ++kt) {
    int cur = kt & 1;
    if (kt < 7) STAGE(cur ^ 1, kt + 1);
    const char* Ab = AbufB + cur * 6144;
    const char* Bb = BbufB + cur * 16384;
#pragma unroll
    for (int ks = 0; ks < 2; ++ks) {
      int kb = ks * 64 + (lg << 4);
      bf16x8 av[3], bv[2];
#pragma unroll
      for (int mt = 0; mt < 3; ++mt) {
        int row = mt * 16 + c16;
        av[mt] = *(const bf16x8*)(Ab + row * 128 + (kb ^ ((row & 7) << 4)));
      }
#pragma unroll
      for (int nt = 0; nt < 2; ++nt) {
        int g = wave * 32 + nt * 16 + c16;
        bv[nt] = *(const bf16x8*)(Bb + g * 128 + (kb ^ ((g & 7) << 4)));
      }
#pragma unroll
      for (int mt = 0; mt < 3; ++mt)
#pragma unroll
        for (int nt = 0; nt < 2; ++nt)
          acc[mt][nt] = __builtin_amdgcn_mfma_f32_16x16x32_bf16(av[mt], bv[nt], acc[mt][nt], 0, 0, 0);
    }
    __syncthreads();
  }

  // ---- epilogue: T rows 0..32 -> LDS ----
  float* T_lds = (float*)smem;            // [33][132]
  float* c_lds = (float*)(smem + 17424);  // [128]
  float* Gp = (float*)(smem + 17936);     // [4][64][16]

#pragma unroll
  for (int mt = 0; mt < 3; ++mt)
#pragma unroll
    for (int nt = 0; nt < 2; ++nt)
#pragma unroll
      for (int r = 0; r < 4; ++r) {
        int row = mt * 16 + lg * 4 + r;
        if (row < 33) {
          int col = wave * 32 + nt * 16 + c16;
          T_lds[row * 132 + col] = acc[mt][nt][r];
        }
      }
  __syncthreads();

  // ---- per-gene c = theta/(mu(mu+theta)+eps) * sig^2 ----
  if (t < 128) {
    int gg = g0 + t;
    float cval = 0.f;
    if (gg < 4000) {
      float s = b2[gg] + T_lds[32 * 132 + t];
#pragma unroll
      for (int i = 0; i < 32; ++i) s = fmaf(zs[i], T_lds[i * 132 + t], s);
      float theta = expf(log_theta[gg]);
      float sig = 1.f / (1.f + expf(-s));
      float mu = (s > 20.f) ? s : log1pf(expf(s));
      float w = theta / (mu * (mu + theta) + 1e-6f);
      cval = w * sig * sig;
    }
    c_lds[t] = cval;
  }
  __syncthreads();

  // ---- Gram partial: 4x4 register block per thread, 4 g-ranges ----
  {
    const int gr = t >> 6;
    const int tb = t & 63;
    const int i0 = (tb >> 3) << 2;
    const int j0 = (tb & 7) << 2;
    float S[16];
#pragma unroll
    for (int e = 0; e < 16; ++e) S[e] = 0.f;
#pragma unroll
    for (int gs = 0; gs < 8; ++gs) {
      int g = gr * 32 + gs * 4;
      f32x4 cv = *(const f32x4*)(c_lds + g);
      f32x4 Ti[4], Tj[4];
#pragma unroll
      for (int r = 0; r < 4; ++r) {
        Ti[r] = *(const f32x4*)(T_lds + (i0 + r) * 132 + g);
        Tj[r] = *(const f32x4*)(T_lds + (j0 + r) * 132 + g);
      }
#pragma unroll
      for (int r = 0; r < 4; ++r) {
        f32x4 ct = cv * Ti[r];
#pragma unroll
        for (int q = 0; q < 4; ++q) {
          f32x4 p = ct * Tj[q];
          S[r * 4 + q] += p[0] + p[1] + p[2] + p[3];
        }
      }
    }
    float* gp = Gp + (gr * 64 + tb) * 16;
#pragma unroll
    for (int e = 0; e < 16; ++e) gp[e] = S[e];
  }
  __syncthreads();

#pragma unroll
  for (int k = 0; k < 4; ++k) {
    int e = t + k * 256;
    int i = e >> 5, j = e & 31;
    int tb2 = ((i >> 2) << 3) | (j >> 2);
    int slot = ((i & 3) << 2) | (j & 3);
    float v = Gp[(0 * 64 + tb2) * 16 + slot] + Gp[(1 * 64 + tb2) * 16 + slot] +
              Gp[(2 * 64 + tb2) * 16 + slot] + Gp[(3 * 64 + tb2) * 16 + slot];
    atomicAdd(Gram + (size_t)b * 1024 + e, v);
  }
}

// ---------------- loss reduce ----------------
__global__ __launch_bounds__(256) void k_loss(const float* __restrict__ Gram,
                                              float* __restrict__ out) {
  __shared__ float red[4];
  const int b = blockIdx.x, t = threadIdx.x;
  float local = 0.f;
#pragma unroll
  for (int k = 0; k < 4; ++k) {
    int e = t + k * 256;
    float d = Gram[(size_t)b * 1024 + e] - (((e >> 5) == (e & 31)) ? 1.f : 0.f);
    local += d * d;
  }
#pragma unroll
  for (int off = 32; off > 0; off >>= 1) local += __shfl_down(local, off);
  if ((t & 63) == 0) red[t >> 6] = local;
  __syncthreads();
  if (t == 0) {
    float s = red[0] + red[1] + red[2] + red[3];
    atomicAdd(out, s * (1.f / 256.f));
  }
}

extern "C" void kernel_launch(void* const* d_in, const int* in_sizes, int n_in,
                              void* d_out, int out_size, void* d_ws, size_t ws_size,
                              hipStream_t stream) {
  const float* z = (const float*)d_in[0];
  const float* W1 = (const float*)d_in[1];
  const float* b1 = (const float*)d_in[2];
  const float* W2 = (const float*)d_in[3];
  const float* b2 = (const float*)d_in[4];
  const float* lt = (const float*)d_in[5];

  char* ws = (char*)d_ws;
  unsigned short* W2T = (unsigned short*)ws;                  // 4096*512*2    = 4,194,304
  unsigned short* Abig = (unsigned short*)(ws + 4194304);     // 256*48*512*2  = 12,582,912
  unsigned char* maskb = (unsigned char*)(ws + 16777216);     // 256*512       = 131,072
  unsigned short* rowb1 = (unsigned short*)(ws + 16908288);   // 256*512*2     = 262,144
  float* Gram = (float*)(ws + 17170432);                      // 256*1024*4    = 1,048,576

  hipMemsetAsync(Gram, 0, 256 * 1024 * 4, stream);
  hipMemsetAsync(d_out, 0, 4, stream);

  k_w2t<<<dim3(64, 8), 256, 0, stream>>>(W2, W2T);
  k_mask<<<256, 256, 0, stream>>>(z, W1, b1, maskb, rowb1);
  k_abig<<<256, 256, 0, stream>>>(W1, maskb, rowb1, Abig);
  k_gemm<<<dim3(256, 32), 256, 0, stream>>>(Abig, W2T, z, b2, lt, Gram);
  k_loss<<<256, 256, 0, stream>>>(Gram, (float*)d_out);
}

// Round 2
// 166.018 us; speedup vs baseline: 2.4998x; 2.4998x over previous
//
#include <hip/hip_runtime.h>

typedef __bf16 bf16x8 __attribute__((ext_vector_type(8)));
typedef float f32x4 __attribute__((ext_vector_type(4)));
typedef unsigned short u16x8 __attribute__((ext_vector_type(8)));

typedef const void __attribute__((address_space(1)))* gas_ptr;
typedef void __attribute__((address_space(3)))* las_ptr;

#define GLOAD16(gp, lp) __builtin_amdgcn_global_load_lds((gas_ptr)(gp), (las_ptr)(lp), 16, 0, 0)

__device__ __forceinline__ unsigned short f2bf(float f) {
  unsigned int u = __float_as_uint(f);
  u += 0x7FFF + ((u >> 16) & 1);
  return (unsigned short)(u >> 16);
}
__device__ __forceinline__ float bf2f(unsigned short u) {
  return __uint_as_float(((unsigned int)u) << 16);
}

// ---------------- prep: W2 [512][4000] f32 -> W2T [4096][512] bf16 (zero-padded) ----------------
__global__ __launch_bounds__(256) void k_w2t(const float* __restrict__ W2,
                                             unsigned short* __restrict__ W2T) {
  __shared__ float tile[64][65];
  const int gt = blockIdx.x;   // 64 tiles of 64 genes
  const int jt = blockIdx.y;   // 8 tiles of 64 j
  const int t = threadIdx.x;
  const int c = t & 63, r4 = t >> 6;
#pragma unroll
  for (int r = 0; r < 16; ++r) {
    int jj = r * 4 + r4;
    int g = gt * 64 + c;
    tile[jj][c] = (g < 4000) ? W2[(size_t)(jt * 64 + jj) * 4000 + g] : 0.f;
  }
  __syncthreads();
#pragma unroll
  for (int r = 0; r < 16; ++r) {
    int gg = r * 4 + r4;
    W2T[(size_t)(gt * 64 + gg) * 512 + jt * 64 + c] = f2bf(tile[c][gg]);
  }
}

// ---------------- prep: mask + h row (bf16) ----------------
__global__ __launch_bounds__(256) void k_mask(const float* __restrict__ z,
                                              const float* __restrict__ W1,
                                              const float* __restrict__ b1,
                                              unsigned char* __restrict__ maskb,
                                              unsigned short* __restrict__ Hb) {
  __shared__ float zs[32];
  const int b = blockIdx.x, t = threadIdx.x;
  if (t < 32) zs[t] = z[b * 32 + t];
  __syncthreads();
#pragma unroll
  for (int jj = 0; jj < 2; ++jj) {
    int j = t + jj * 256;
    float a = b1[j];
#pragma unroll
    for (int i = 0; i < 32; ++i) a = fmaf(zs[i], W1[i * 512 + j], a);
    bool m = a > 0.f;
    maskb[b * 512 + j] = m ? 1 : 0;
    Hb[b * 512 + j] = m ? f2bf(a) : (unsigned short)0;
  }
}

// ---------------- prep: Astack [256*32][512] bf16 = per-sample mask ⊙ W1 rows ----------------
__global__ __launch_bounds__(256) void k_abig(const float* __restrict__ W1,
                                              const unsigned char* __restrict__ maskb,
                                              unsigned short* __restrict__ Astack) {
  const int b = blockIdx.x, t = threadIdx.x;
#pragma unroll
  for (int k = 0; k < 8; ++k) {
    int c8 = t + k * 256;      // 0..2047
    int row = c8 >> 6;         // 0..31
    int k8 = (c8 & 63) * 8;    // 0..504
    unsigned long long m8 = *(const unsigned long long*)(maskb + b * 512 + k8);
    const float* w = W1 + row * 512 + k8;
    u16x8 out;
#pragma unroll
    for (int e = 0; e < 8; ++e)
      out[e] = ((m8 >> (e * 8)) & 0xffULL) ? f2bf(w[e]) : (unsigned short)0;
    *(u16x8*)(Astack + ((size_t)(b * 32 + row)) * 512 + k8) = out;
  }
}

// ---------------- k_s: S = H @ W2T^T + b2 -> per-gene weight c = w*sig^2 ----------------
// grid (4 sample-tiles of 64, 32 gene-tiles of 128), 256 threads
__global__ __launch_bounds__(256) void k_s(const unsigned short* __restrict__ Hb,
                                           const unsigned short* __restrict__ W2T,
                                           const float* __restrict__ b2,
                                           const float* __restrict__ log_theta,
                                           float* __restrict__ Cw) {
  __shared__ __align__(16) char smem[49152];
  char* Abuf = smem;            // 2 * 8192
  char* Bbuf = smem + 16384;    // 2 * 16384

  const int bm = blockIdx.x;
  const int g0 = blockIdx.y * 128;
  const int t = threadIdx.x;
  const int lane = t & 63;
  const int wave = t >> 6;
  const int l8 = lane >> 3;
  const int kxor = (((lane & 7) ^ l8) << 3);
  const int c16 = lane & 15;
  const int lg = lane >> 4;

  f32x4 acc[4][2];
#pragma unroll
  for (int mt = 0; mt < 4; ++mt)
#pragma unroll
    for (int nt = 0; nt < 2; ++nt) acc[mt][nt] = (f32x4){0.f, 0.f, 0.f, 0.f};

#define STAGE_S(buf, kt)                                                              \
  do {                                                                                \
    _Pragma("unroll") for (int qq = 0; qq < 2; ++qq) {                                \
      int q = wave * 2 + qq;                                                          \
      GLOAD16(Hb + (size_t)(bm * 64 + q * 8 + l8) * 512 + (kt) * 64 + kxor,           \
              Abuf + (buf) * 8192 + q * 1024);                                        \
    }                                                                                 \
    _Pragma("unroll") for (int qq = 0; qq < 4; ++qq) {                                \
      int q = wave * 4 + qq;                                                          \
      GLOAD16(W2T + (size_t)(g0 + q * 8 + l8) * 512 + (kt) * 64 + kxor,               \
              Bbuf + (buf) * 16384 + q * 1024);                                       \
    }                                                                                 \
  } while (0)

  STAGE_S(0, 0);
  __syncthreads();

  for (int kt = 0; kt < 8; ++kt) {
    int cur = kt & 1;
    if (kt < 7) STAGE_S(cur ^ 1, kt + 1);
    const char* Ab = Abuf + cur * 8192;
    const char* Bb = Bbuf + cur * 16384;
#pragma unroll
    for (int ks = 0; ks < 2; ++ks) {
      int kb = ks * 64 + lg * 16;
      bf16x8 av[4], bv[2];
#pragma unroll
      for (int mt = 0; mt < 4; ++mt) {
        int row = mt * 16 + c16;
        av[mt] = *(const bf16x8*)(Ab + (row >> 3) * 1024 + (row & 7) * 128 + (kb ^ ((row & 7) << 4)));
      }
#pragma unroll
      for (int nt = 0; nt < 2; ++nt) {
        int row = wave * 32 + nt * 16 + c16;
        bv[nt] = *(const bf16x8*)(Bb + (row >> 3) * 1024 + (row & 7) * 128 + (kb ^ ((row & 7) << 4)));
      }
#pragma unroll
      for (int mt = 0; mt < 4; ++mt)
#pragma unroll
        for (int nt = 0; nt < 2; ++nt)
          acc[mt][nt] = __builtin_amdgcn_mfma_f32_16x16x32_bf16(av[mt], bv[nt], acc[mt][nt], 0, 0, 0);
    }
    __syncthreads();
  }

  // epilogue: s -> c
#pragma unroll
  for (int nt = 0; nt < 2; ++nt) {
    int g = g0 + wave * 32 + nt * 16 + c16;
    if (g < 4000) {
      float bb = b2[g];
      float theta = expf(log_theta[g]);
#pragma unroll
      for (int mt = 0; mt < 4; ++mt)
#pragma unroll
        for (int r = 0; r < 4; ++r) {
          int sample = bm * 64 + mt * 16 + lg * 4 + r;
          float s = acc[mt][nt][r] + bb;
          float sig = 1.f / (1.f + expf(-s));
          float mu = (s > 20.f) ? s : log1pf(expf(s));
          float w = theta / (mu * (mu + theta) + 1e-6f);
          Cw[(size_t)sample * 4096 + g] = w * sig * sig;
        }
    } else {
#pragma unroll
      for (int mt = 0; mt < 4; ++mt)
#pragma unroll
        for (int r = 0; r < 4; ++r) {
          int sample = bm * 64 + mt * 16 + lg * 4 + r;
          Cw[(size_t)sample * 4096 + g] = 0.f;
        }
    }
  }
}

// ---------------- main GEMM: T = Astack @ W2T^T, fused Gram epilogue ----------------
// grid (64 M-tiles of 128 rows = 4 samples, 32 N-tiles of 128 genes), 256 threads
__global__ __launch_bounds__(256, 2) void k_gemm(const unsigned short* __restrict__ Astack,
                                                 const unsigned short* __restrict__ W2T,
                                                 const float* __restrict__ Cw,
                                                 float* __restrict__ Gram) {
  __shared__ __align__(16) char smem[65536];
  char* AbufB = smem;             // 2 * 16384
  char* BbufB = smem + 32768;     // 2 * 16384

  const int bm = blockIdx.x;
  const int g0 = blockIdx.y * 128;
  const int t = threadIdx.x;
  const int lane = t & 63;
  const int wave = t >> 6;
  const int wr = wave >> 1, wc = wave & 1;
  const int l8 = lane >> 3;
  const int kxor = (((lane & 7) ^ l8) << 3);
  const int c16 = lane & 15;
  const int lg = lane >> 4;

  f32x4 acc[4][4];
#pragma unroll
  for (int mt = 0; mt < 4; ++mt)
#pragma unroll
    for (int nt = 0; nt < 4; ++nt) acc[mt][nt] = (f32x4){0.f, 0.f, 0.f, 0.f};

  const size_t Abase = (size_t)bm * 128 * 512;

#define STAGE_G(buf, kt)                                                              \
  do {                                                                                \
    _Pragma("unroll") for (int qq = 0; qq < 4; ++qq) {                                \
      int q = wave * 4 + qq;                                                          \
      GLOAD16(Astack + Abase + (size_t)(q * 8 + l8) * 512 + (kt) * 64 + kxor,         \
              AbufB + (buf) * 16384 + q * 1024);                                      \
    }                                                                                 \
    _Pragma("unroll") for (int qq = 0; qq < 4; ++qq) {                                \
      int q = wave * 4 + qq;                                                          \
      GLOAD16(W2T + (size_t)(g0 + q * 8 + l8) * 512 + (kt) * 64 + kxor,               \
              BbufB + (buf) * 16384 + q * 1024);                                      \
    }                                                                                 \
  } while (0)

  STAGE_G(0, 0);
  __syncthreads();

  for (int kt = 0; kt < 8; ++kt) {
    int cur = kt & 1;
    if (kt < 7) STAGE_G(cur ^ 1, kt + 1);
    const char* Ab = AbufB + cur * 16384;
    const char* Bb = BbufB + cur * 16384;
#pragma unroll
    for (int ks = 0; ks < 2; ++ks) {
      int kb = ks * 64 + lg * 16;
      bf16x8 av[4], bv[4];
#pragma unroll
      for (int mt = 0; mt < 4; ++mt) {
        int row = wr * 64 + mt * 16 + c16;
        av[mt] = *(const bf16x8*)(Ab + (row >> 3) * 1024 + (row & 7) * 128 + (kb ^ ((row & 7) << 4)));
      }
#pragma unroll
      for (int nt = 0; nt < 4; ++nt) {
        int row = wc * 64 + nt * 16 + c16;
        bv[nt] = *(const bf16x8*)(Bb + (row >> 3) * 1024 + (row & 7) * 128 + (kb ^ ((row & 7) << 4)));
      }
#pragma unroll
      for (int mt = 0; mt < 4; ++mt)
#pragma unroll
        for (int nt = 0; nt < 4; ++nt)
          acc[mt][nt] = __builtin_amdgcn_mfma_f32_16x16x32_bf16(av[mt], bv[nt], acc[mt][nt], 0, 0, 0);
    }
    __syncthreads();
  }

  // ---- epilogue: T tile (bf16) -> LDS [128][136], c weights -> LDS ----
  unsigned short* T = (unsigned short*)smem;        // 128*136*2 = 34816 B
  float* c_lds = (float*)(smem + 34816);            // [4][128] = 2048 B

#pragma unroll
  for (int mt = 0; mt < 4; ++mt)
#pragma unroll
    for (int nt = 0; nt < 4; ++nt)
#pragma unroll
      for (int r = 0; r < 4; ++r) {
        int row = wr * 64 + mt * 16 + lg * 4 + r;
        int col = wc * 64 + nt * 16 + c16;
        T[row * 136 + col] = f2bf(acc[mt][nt][r]);
      }
#pragma unroll
  for (int k = 0; k < 2; ++k) {
    int e = t + k * 256;
    c_lds[e] = Cw[(size_t)(bm * 4 + (e >> 7)) * 4096 + g0 + (e & 127)];
  }
  __syncthreads();

  // ---- Gram via MFMA: wave w owns sample w; Gram32x32 += (c*T) @ T^T over 128 genes ----
  {
    const int s = wave;
    f32x4 gacc[2][2];
#pragma unroll
    for (int m2 = 0; m2 < 2; ++m2)
#pragma unroll
      for (int n2 = 0; n2 < 2; ++n2) gacc[m2][n2] = (f32x4){0.f, 0.f, 0.f, 0.f};

#pragma unroll
    for (int ch = 0; ch < 4; ++ch) {
      u16x8 raw[2];
      bf16x8 ap[2], bp[2];
      f32x4 cv0 = *(const f32x4*)(c_lds + s * 128 + ch * 32 + lg * 8);
      f32x4 cv1 = *(const f32x4*)(c_lds + s * 128 + ch * 32 + lg * 8 + 4);
#pragma unroll
      for (int m2 = 0; m2 < 2; ++m2) {
        int row = s * 32 + m2 * 16 + c16;
        raw[m2] = *(const u16x8*)((const char*)T + row * 272 + ch * 64 + lg * 16);
        u16x8 sc;
#pragma unroll
        for (int e = 0; e < 4; ++e) sc[e] = f2bf(bf2f(raw[m2][e]) * cv0[e]);
#pragma unroll
        for (int e = 0; e < 4; ++e) sc[4 + e] = f2bf(bf2f(raw[m2][4 + e]) * cv1[e]);
        ap[m2] = __builtin_bit_cast(bf16x8, sc);
        bp[m2] = __builtin_bit_cast(bf16x8, raw[m2]);
      }
#pragma unroll
      for (int m2 = 0; m2 < 2; ++m2)
#pragma unroll
        for (int n2 = 0; n2 < 2; ++n2)
          gacc[m2][n2] = __builtin_amdgcn_mfma_f32_16x16x32_bf16(ap[m2], bp[n2], gacc[m2][n2], 0, 0, 0);
    }

#pragma unroll
    for (int m2 = 0; m2 < 2; ++m2)
#pragma unroll
      for (int n2 = 0; n2 < 2; ++n2)
#pragma unroll
        for (int r = 0; r < 4; ++r) {
          int i = m2 * 16 + lg * 4 + r;
          int j = n2 * 16 + c16;
          atomicAdd(Gram + (size_t)(bm * 4 + s) * 1024 + i * 32 + j, gacc[m2][n2][r]);
        }
  }
}

// ---------------- loss reduce ----------------
__global__ __launch_bounds__(256) void k_loss(const float* __restrict__ Gram,
                                              float* __restrict__ out) {
  __shared__ float red[4];
  const int b = blockIdx.x, t = threadIdx.x;
  float local = 0.f;
#pragma unroll
  for (int k = 0; k < 4; ++k) {
    int e = t + k * 256;
    float d = Gram[(size_t)b * 1024 + e] - (((e >> 5) == (e & 31)) ? 1.f : 0.f);
    local += d * d;
  }
#pragma unroll
  for (int off = 32; off > 0; off >>= 1) local += __shfl_down(local, off);
  if ((t & 63) == 0) red[t >> 6] = local;
  __syncthreads();
  if (t == 0) {
    float s = red[0] + red[1] + red[2] + red[3];
    atomicAdd(out, s * (1.f / 256.f));
  }
}

extern "C" void kernel_launch(void* const* d_in, const int* in_sizes, int n_in,
                              void* d_out, int out_size, void* d_ws, size_t ws_size,
                              hipStream_t stream) {
  const float* z = (const float*)d_in[0];
  const float* W1 = (const float*)d_in[1];
  const float* b1 = (const float*)d_in[2];
  const float* W2 = (const float*)d_in[3];
  const float* b2 = (const float*)d_in[4];
  const float* lt = (const float*)d_in[5];

  char* ws = (char*)d_ws;
  unsigned short* W2T = (unsigned short*)ws;                   // 4,194,304
  unsigned short* Astack = (unsigned short*)(ws + 4194304);    // 8,388,608
  unsigned short* Hb = (unsigned short*)(ws + 12582912);       // 262,144
  unsigned char* maskb = (unsigned char*)(ws + 12845056);      // 131,072
  float* Cw = (float*)(ws + 12976128);                         // 4,194,304
  float* Gram = (float*)(ws + 17170432);                       // 1,048,576

  hipMemsetAsync(Gram, 0, 256 * 1024 * 4, stream);
  hipMemsetAsync(d_out, 0, 4, stream);

  k_w2t<<<dim3(64, 8), 256, 0, stream>>>(W2, W2T);
  k_mask<<<256, 256, 0, stream>>>(z, W1, b1, maskb, Hb);
  k_abig<<<256, 256, 0, stream>>>(W1, maskb, Astack);
  k_s<<<dim3(4, 32), 256, 0, stream>>>(Hb, W2T, b2, lt, Cw);
  k_gemm<<<dim3(64, 32), 256, 0, stream>>>(Astack, W2T, Cw, Gram);
  k_loss<<<256, 256, 0, stream>>>(Gram, (float*)d_out);
}

// Round 3
// 159.922 us; speedup vs baseline: 2.5951x; 1.0381x over previous
//
#include <hip/hip_runtime.h>

typedef __bf16 bf16x8 __attribute__((ext_vector_type(8)));
typedef float f32x4 __attribute__((ext_vector_type(4)));
typedef unsigned short u16x8 __attribute__((ext_vector_type(8)));

typedef const void __attribute__((address_space(1)))* gas_ptr;
typedef void __attribute__((address_space(3)))* las_ptr;

#define GLOAD16(gp, lp) __builtin_amdgcn_global_load_lds((gas_ptr)(gp), (las_ptr)(lp), 16, 0, 0)

__device__ __forceinline__ unsigned short f2bf(float f) {
  unsigned int u = __float_as_uint(f);
  u += 0x7FFF + ((u >> 16) & 1);
  return (unsigned short)(u >> 16);
}
__device__ __forceinline__ float bf2f(unsigned short u) {
  return __uint_as_float(((unsigned int)u) << 16);
}

// ---------------- prep: W2 [512][4000] f32 -> W2T [4096][512] bf16 (zero-padded) ----------------
__global__ __launch_bounds__(256) void k_w2t(const float* __restrict__ W2,
                                             unsigned short* __restrict__ W2T) {
  __shared__ float tile[64][65];
  const int gt = blockIdx.x;   // 64 tiles of 64 genes
  const int jt = blockIdx.y;   // 8 tiles of 64 j
  const int t = threadIdx.x;
  const int c = t & 63, r4 = t >> 6;
#pragma unroll
  for (int r = 0; r < 16; ++r) {
    int jj = r * 4 + r4;
    int g = gt * 64 + c;
    tile[jj][c] = (g < 4000) ? W2[(size_t)(jt * 64 + jj) * 4000 + g] : 0.f;
  }
  __syncthreads();
#pragma unroll
  for (int r = 0; r < 16; ++r) {
    int gg = r * 4 + r4;
    W2T[(size_t)(gt * 64 + gg) * 512 + jt * 64 + c] = f2bf(tile[c][gg]);
  }
}

// ---------------- prep: mask + h row (bf16) ----------------
__global__ __launch_bounds__(256) void k_mask(const float* __restrict__ z,
                                              const float* __restrict__ W1,
                                              const float* __restrict__ b1,
                                              unsigned char* __restrict__ maskb,
                                              unsigned short* __restrict__ Hb) {
  __shared__ float zs[32];
  const int b = blockIdx.x, t = threadIdx.x;
  if (t < 32) zs[t] = z[b * 32 + t];
  __syncthreads();
#pragma unroll
  for (int jj = 0; jj < 2; ++jj) {
    int j = t + jj * 256;
    float a = b1[j];
#pragma unroll
    for (int i = 0; i < 32; ++i) a = fmaf(zs[i], W1[i * 512 + j], a);
    bool m = a > 0.f;
    maskb[b * 512 + j] = m ? 1 : 0;
    Hb[b * 512 + j] = m ? f2bf(a) : (unsigned short)0;
  }
}

// ---------------- prep: Astack [256*32][512] bf16 = per-sample mask ⊙ W1 rows ----------------
__global__ __launch_bounds__(256) void k_abig(const float* __restrict__ W1,
                                              const unsigned char* __restrict__ maskb,
                                              unsigned short* __restrict__ Astack) {
  const int b = blockIdx.x, t = threadIdx.x;
#pragma unroll
  for (int k = 0; k < 8; ++k) {
    int c8 = t + k * 256;      // 0..2047
    int row = c8 >> 6;         // 0..31
    int k8 = (c8 & 63) * 8;    // 0..504
    unsigned long long m8 = *(const unsigned long long*)(maskb + b * 512 + k8);
    const float* w = W1 + row * 512 + k8;
    u16x8 out;
#pragma unroll
    for (int e = 0; e < 8; ++e)
      out[e] = ((m8 >> (e * 8)) & 0xffULL) ? f2bf(w[e]) : (unsigned short)0;
    *(u16x8*)(Astack + ((size_t)(b * 32 + row)) * 512 + k8) = out;
  }
}

// ---------------- k_s2: register-tiled S = H @ W2T^T + b2 -> Cw, no LDS, no barriers ----------
// 512 WGs x 256 thr = 2048 waves; each wave: 16 samples x 32 genes, K=512
__global__ __launch_bounds__(256) void k_s2(const unsigned short* __restrict__ Hb,
                                            const unsigned short* __restrict__ W2T,
                                            const float* __restrict__ b2,
                                            const float* __restrict__ log_theta,
                                            float* __restrict__ Cw) {
  const int t = threadIdx.x;
  const int lane = t & 63;
  const int wave = t >> 6;
  const int wid = blockIdx.x * 4 + wave;   // 0..2047
  const int st = wid >> 7;                 // 0..15 : 16-sample tile
  const int gt = wid & 127;                // 0..127: 32-gene tile
  const int c16 = lane & 15, lg = lane >> 4;
  const int s0 = st * 16, g0 = gt * 32;

  // preload all A fragments for this wave's 16 sample-rows (row = s0+c16, k-chunk = lg*8 + ks*32)
  bf16x8 av[16];
  {
    const unsigned short* Arow = Hb + (size_t)(s0 + c16) * 512 + lg * 8;
#pragma unroll
    for (int ks = 0; ks < 16; ++ks) av[ks] = *(const bf16x8*)(Arow + ks * 32);
  }

  f32x4 acc[2];
  acc[0] = (f32x4){0.f, 0.f, 0.f, 0.f};
  acc[1] = (f32x4){0.f, 0.f, 0.f, 0.f};

  const unsigned short* B0 = W2T + (size_t)(g0 + c16) * 512 + lg * 8;
  const unsigned short* B1 = B0 + 16 * 512;
#pragma unroll
  for (int ks = 0; ks < 16; ++ks) {
    bf16x8 b0 = *(const bf16x8*)(B0 + ks * 32);
    bf16x8 b1 = *(const bf16x8*)(B1 + ks * 32);
    acc[0] = __builtin_amdgcn_mfma_f32_16x16x32_bf16(av[ks], b0, acc[0], 0, 0, 0);
    acc[1] = __builtin_amdgcn_mfma_f32_16x16x32_bf16(av[ks], b1, acc[1], 0, 0, 0);
  }

  // epilogue: acc[n][r] = S[s0 + lg*4 + r][g0 + n*16 + c16] (minus b2)
#pragma unroll
  for (int n = 0; n < 2; ++n) {
    int g = g0 + n * 16 + c16;
    if (g < 4000) {
      float bb = b2[g];
      float theta = expf(log_theta[g]);
#pragma unroll
      for (int r = 0; r < 4; ++r) {
        int sample = s0 + lg * 4 + r;
        float s = acc[n][r] + bb;
        float sig = 1.f / (1.f + expf(-s));
        float mu = (s > 20.f) ? s : log1pf(expf(s));
        float w = theta / (mu * (mu + theta) + 1e-6f);
        Cw[(size_t)sample * 4096 + g] = w * sig * sig;
      }
    } else {
#pragma unroll
      for (int r = 0; r < 4; ++r) {
        int sample = s0 + lg * 4 + r;
        Cw[(size_t)sample * 4096 + g] = 0.f;
      }
    }
  }
}

// ---------------- main GEMM: T = Astack @ W2T^T, fused Gram epilogue ----------------
// grid (64 M-tiles of 128 rows = 4 samples, 32 N-tiles of 128 genes), 256 threads
__global__ __launch_bounds__(256, 2) void k_gemm(const unsigned short* __restrict__ Astack,
                                                 const unsigned short* __restrict__ W2T,
                                                 const float* __restrict__ Cw,
                                                 float* __restrict__ Gram) {
  __shared__ __align__(16) char smem[65536];
  char* AbufB = smem;             // 2 * 16384
  char* BbufB = smem + 32768;     // 2 * 16384

  const int bm = blockIdx.x;
  const int g0 = blockIdx.y * 128;
  const int t = threadIdx.x;
  const int lane = t & 63;
  const int wave = t >> 6;
  const int wr = wave >> 1, wc = wave & 1;
  const int l8 = lane >> 3;
  const int kxor = (((lane & 7) ^ l8) << 3);
  const int c16 = lane & 15;
  const int lg = lane >> 4;

  f32x4 acc[4][4];
#pragma unroll
  for (int mt = 0; mt < 4; ++mt)
#pragma unroll
    for (int nt = 0; nt < 4; ++nt) acc[mt][nt] = (f32x4){0.f, 0.f, 0.f, 0.f};

  const size_t Abase = (size_t)bm * 128 * 512;

#define STAGE_G(buf, kt)                                                              \
  do {                                                                                \
    _Pragma("unroll") for (int qq = 0; qq < 4; ++qq) {                                \
      int q = wave * 4 + qq;                                                          \
      GLOAD16(Astack + Abase + (size_t)(q * 8 + l8) * 512 + (kt) * 64 + kxor,         \
              AbufB + (buf) * 16384 + q * 1024);                                      \
    }                                                                                 \
    _Pragma("unroll") for (int qq = 0; qq < 4; ++qq) {                                \
      int q = wave * 4 + qq;                                                          \
      GLOAD16(W2T + (size_t)(g0 + q * 8 + l8) * 512 + (kt) * 64 + kxor,               \
              BbufB + (buf) * 16384 + q * 1024);                                      \
    }                                                                                 \
  } while (0)

  STAGE_G(0, 0);
  __syncthreads();

  for (int kt = 0; kt < 8; ++kt) {
    int cur = kt & 1;
    if (kt < 7) STAGE_G(cur ^ 1, kt + 1);
    const char* Ab = AbufB + cur * 16384;
    const char* Bb = BbufB + cur * 16384;
#pragma unroll
    for (int ks = 0; ks < 2; ++ks) {
      int kb = ks * 64 + lg * 16;
      bf16x8 av[4], bv[4];
#pragma unroll
      for (int mt = 0; mt < 4; ++mt) {
        int row = wr * 64 + mt * 16 + c16;
        av[mt] = *(const bf16x8*)(Ab + (row >> 3) * 1024 + (row & 7) * 128 + (kb ^ ((row & 7) << 4)));
      }
#pragma unroll
      for (int nt = 0; nt < 4; ++nt) {
        int row = wc * 64 + nt * 16 + c16;
        bv[nt] = *(const bf16x8*)(Bb + (row >> 3) * 1024 + (row & 7) * 128 + (kb ^ ((row & 7) << 4)));
      }
#pragma unroll
      for (int mt = 0; mt < 4; ++mt)
#pragma unroll
        for (int nt = 0; nt < 4; ++nt)
          acc[mt][nt] = __builtin_amdgcn_mfma_f32_16x16x32_bf16(av[mt], bv[nt], acc[mt][nt], 0, 0, 0);
    }
    __syncthreads();
  }

  // ---- epilogue: T tile (bf16) -> LDS [128][136], c weights -> LDS ----
  unsigned short* T = (unsigned short*)smem;        // 128*136*2 = 34816 B
  float* c_lds = (float*)(smem + 34816);            // [4][128] = 2048 B

#pragma unroll
  for (int mt = 0; mt < 4; ++mt)
#pragma unroll
    for (int nt = 0; nt < 4; ++nt)
#pragma unroll
      for (int r = 0; r < 4; ++r) {
        int row = wr * 64 + mt * 16 + lg * 4 + r;
        int col = wc * 64 + nt * 16 + c16;
        T[row * 136 + col] = f2bf(acc[mt][nt][r]);
      }
#pragma unroll
  for (int k = 0; k < 2; ++k) {
    int e = t + k * 256;
    c_lds[e] = Cw[(size_t)(bm * 4 + (e >> 7)) * 4096 + g0 + (e & 127)];
  }
  __syncthreads();

  // ---- Gram via MFMA: wave w owns sample w; Gram32x32 += (c*T) @ T^T over 128 genes ----
  {
    const int s = wave;
    f32x4 gacc[2][2];
#pragma unroll
    for (int m2 = 0; m2 < 2; ++m2)
#pragma unroll
      for (int n2 = 0; n2 < 2; ++n2) gacc[m2][n2] = (f32x4){0.f, 0.f, 0.f, 0.f};

#pragma unroll
    for (int ch = 0; ch < 4; ++ch) {
      u16x8 raw[2];
      bf16x8 ap[2], bp[2];
      f32x4 cv0 = *(const f32x4*)(c_lds + s * 128 + ch * 32 + lg * 8);
      f32x4 cv1 = *(const f32x4*)(c_lds + s * 128 + ch * 32 + lg * 8 + 4);
#pragma unroll
      for (int m2 = 0; m2 < 2; ++m2) {
        int row = s * 32 + m2 * 16 + c16;
        raw[m2] = *(const u16x8*)((const char*)T + row * 272 + ch * 64 + lg * 16);
        u16x8 sc;
#pragma unroll
        for (int e = 0; e < 4; ++e) sc[e] = f2bf(bf2f(raw[m2][e]) * cv0[e]);
#pragma unroll
        for (int e = 0; e < 4; ++e) sc[4 + e] = f2bf(bf2f(raw[m2][4 + e]) * cv1[e]);
        ap[m2] = __builtin_bit_cast(bf16x8, sc);
        bp[m2] = __builtin_bit_cast(bf16x8, raw[m2]);
      }
#pragma unroll
      for (int m2 = 0; m2 < 2; ++m2)
#pragma unroll
        for (int n2 = 0; n2 < 2; ++n2)
          gacc[m2][n2] = __builtin_amdgcn_mfma_f32_16x16x32_bf16(ap[m2], bp[n2], gacc[m2][n2], 0, 0, 0);
    }

#pragma unroll
    for (int m2 = 0; m2 < 2; ++m2)
#pragma unroll
      for (int n2 = 0; n2 < 2; ++n2)
#pragma unroll
        for (int r = 0; r < 4; ++r) {
          int i = m2 * 16 + lg * 4 + r;
          int j = n2 * 16 + c16;
          atomicAdd(Gram + (size_t)(bm * 4 + s) * 1024 + i * 32 + j, gacc[m2][n2][r]);
        }
  }
}

// ---------------- loss reduce ----------------
__global__ __launch_bounds__(256) void k_loss(const float* __restrict__ Gram,
                                              float* __restrict__ out) {
  __shared__ float red[4];
  const int b = blockIdx.x, t = threadIdx.x;
  float local = 0.f;
#pragma unroll
  for (int k = 0; k < 4; ++k) {
    int e = t + k * 256;
    float d = Gram[(size_t)b * 1024 + e] - (((e >> 5) == (e & 31)) ? 1.f : 0.f);
    local += d * d;
  }
#pragma unroll
  for (int off = 32; off > 0; off >>= 1) local += __shfl_down(local, off);
  if ((t & 63) == 0) red[t >> 6] = local;
  __syncthreads();
  if (t == 0) {
    float s = red[0] + red[1] + red[2] + red[3];
    atomicAdd(out, s * (1.f / 256.f));
  }
}

extern "C" void kernel_launch(void* const* d_in, const int* in_sizes, int n_in,
                              void* d_out, int out_size, void* d_ws, size_t ws_size,
                              hipStream_t stream) {
  const float* z = (const float*)d_in[0];
  const float* W1 = (const float*)d_in[1];
  const float* b1 = (const float*)d_in[2];
  const float* W2 = (const float*)d_in[3];
  const float* b2 = (const float*)d_in[4];
  const float* lt = (const float*)d_in[5];

  char* ws = (char*)d_ws;
  unsigned short* W2T = (unsigned short*)ws;                   // 4,194,304
  unsigned short* Astack = (unsigned short*)(ws + 4194304);    // 8,388,608
  unsigned short* Hb = (unsigned short*)(ws + 12582912);       // 262,144
  unsigned char* maskb = (unsigned char*)(ws + 12845056);      // 131,072
  float* Cw = (float*)(ws + 12976128);                         // 4,194,304
  float* Gram = (float*)(ws + 17170432);                       // 1,048,576

  hipMemsetAsync(Gram, 0, 256 * 1024 * 4, stream);
  hipMemsetAsync(d_out, 0, 4, stream);

  k_w2t<<<dim3(64, 8), 256, 0, stream>>>(W2, W2T);
  k_mask<<<256, 256, 0, stream>>>(z, W1, b1, maskb, Hb);
  k_abig<<<256, 256, 0, stream>>>(W1, maskb, Astack);
  k_s2<<<512, 256, 0, stream>>>(Hb, W2T, b2, lt, Cw);
  k_gemm<<<dim3(64, 32), 256, 0, stream>>>(Astack, W2T, Cw, Gram);
  k_loss<<<256, 256, 0, stream>>>(Gram, (float*)d_out);
}

// Round 4
// 152.904 us; speedup vs baseline: 2.7142x; 1.0459x over previous
//
#include <hip/hip_runtime.h>

typedef __bf16 bf16x8 __attribute__((ext_vector_type(8)));
typedef float f32x4 __attribute__((ext_vector_type(4)));
typedef unsigned short u16x8 __attribute__((ext_vector_type(8)));

typedef const void __attribute__((address_space(1)))* gas_ptr;
typedef void __attribute__((address_space(3)))* las_ptr;

#define GLOAD16(gp, lp) __builtin_amdgcn_global_load_lds((gas_ptr)(gp), (las_ptr)(lp), 16, 0, 0)

__device__ __forceinline__ unsigned short f2bf(float f) {
  unsigned int u = __float_as_uint(f);
  u += 0x7FFF + ((u >> 16) & 1);
  return (unsigned short)(u >> 16);
}
__device__ __forceinline__ float bf2f(unsigned short u) {
  return __uint_as_float(((unsigned int)u) << 16);
}

// ---------------- prep: W2 [512][4000] f32 -> W2T [4096][512] bf16 (zero-padded) ----------------
__global__ __launch_bounds__(256) void k_w2t(const float* __restrict__ W2,
                                             unsigned short* __restrict__ W2T) {
  __shared__ float tile[64][65];
  const int gt = blockIdx.x;   // 64 tiles of 64 genes
  const int jt = blockIdx.y;   // 8 tiles of 64 j
  const int t = threadIdx.x;
  const int c = t & 63, r4 = t >> 6;
#pragma unroll
  for (int r = 0; r < 16; ++r) {
    int jj = r * 4 + r4;
    int g = gt * 64 + c;
    tile[jj][c] = (g < 4000) ? W2[(size_t)(jt * 64 + jj) * 4000 + g] : 0.f;
  }
  __syncthreads();
#pragma unroll
  for (int r = 0; r < 16; ++r) {
    int gg = r * 4 + r4;
    W2T[(size_t)(gt * 64 + gg) * 512 + jt * 64 + c] = f2bf(tile[c][gg]);
  }
}

// ---------------- fused prep: mask + Hb + Astack in one pass ----------------
__global__ __launch_bounds__(256) void k_prep(const float* __restrict__ z,
                                              const float* __restrict__ W1,
                                              const float* __restrict__ b1,
                                              unsigned short* __restrict__ Hb,
                                              unsigned short* __restrict__ Astack) {
  __shared__ float zs[32];
  __shared__ __align__(8) unsigned char mk[512];
  const int b = blockIdx.x, t = threadIdx.x;
  if (t < 32) zs[t] = z[b * 32 + t];
  __syncthreads();
#pragma unroll
  for (int jj = 0; jj < 2; ++jj) {
    int j = t + jj * 256;
    float a = b1[j];
#pragma unroll
    for (int i = 0; i < 32; ++i) a = fmaf(zs[i], W1[i * 512 + j], a);
    bool m = a > 0.f;
    mk[j] = m ? 1 : 0;
    Hb[b * 512 + j] = m ? f2bf(a) : (unsigned short)0;
  }
  __syncthreads();
#pragma unroll
  for (int k = 0; k < 8; ++k) {
    int c8 = t + k * 256;      // 0..2047
    int row = c8 >> 6;         // 0..31
    int k8 = (c8 & 63) * 8;    // 0..504
    unsigned long long m8 = *(const unsigned long long*)(mk + k8);
    const float* w = W1 + row * 512 + k8;
    u16x8 out;
#pragma unroll
    for (int e = 0; e < 8; ++e)
      out[e] = ((m8 >> (e * 8)) & 0xffULL) ? f2bf(w[e]) : (unsigned short)0;
    *(u16x8*)(Astack + ((size_t)(b * 32 + row)) * 512 + k8) = out;
  }
}

// ---------------- k_s3: S = H @ W2T^T + b2 -> Cw ; coalesced LDS staging, 512 WGs ----------
// tile: 32 samples x 64 genes, K=512 in 8 steps of 64; grid (8 m-tiles, 64 n-tiles)
__global__ __launch_bounds__(256) void k_s3(const unsigned short* __restrict__ Hb,
                                            const unsigned short* __restrict__ W2T,
                                            const float* __restrict__ b2,
                                            const float* __restrict__ log_theta,
                                            float* __restrict__ Cw) {
  __shared__ __align__(16) char smem[24576];
  char* Abuf = smem;            // 2 * 4096  (32 rows x 64k)
  char* Bbuf = smem + 8192;     // 2 * 8192  (64 rows x 64k)

  const int bm = blockIdx.x;    // 8 sample tiles of 32
  const int g0 = blockIdx.y * 64;
  const int t = threadIdx.x;
  const int lane = t & 63;
  const int wave = t >> 6;
  const int l8 = lane >> 3;
  const int kxor = (((lane & 7) ^ l8) << 3);   // element offset, pre-swizzled source
  const int c16 = lane & 15;
  const int lg = lane >> 4;

  f32x4 acc[2];
  acc[0] = (f32x4){0.f, 0.f, 0.f, 0.f};
  acc[1] = (f32x4){0.f, 0.f, 0.f, 0.f};

#define STAGE_S3(buf, kt)                                                             \
  do {                                                                                \
    GLOAD16(Hb + (size_t)(bm * 32 + wave * 8 + l8) * 512 + (kt) * 64 + kxor,          \
            Abuf + (buf) * 4096 + wave * 1024);                                       \
    _Pragma("unroll") for (int qq = 0; qq < 2; ++qq) {                                \
      int q = wave * 2 + qq;                                                          \
      GLOAD16(W2T + (size_t)(g0 + q * 8 + l8) * 512 + (kt) * 64 + kxor,               \
              Bbuf + (buf) * 8192 + q * 1024);                                        \
    }                                                                                 \
  } while (0)

  STAGE_S3(0, 0);
  __syncthreads();

  for (int kt = 0; kt < 8; ++kt) {
    int cur = kt & 1;
    if (kt < 7) STAGE_S3(cur ^ 1, kt + 1);
    const char* Ab = Abuf + cur * 4096;
    const char* Bb = Bbuf + cur * 8192;
#pragma unroll
    for (int ks = 0; ks < 2; ++ks) {
      int kb = ks * 64 + lg * 16;   // byte offset within 128B row
      bf16x8 av[2], bv;
#pragma unroll
      for (int mt = 0; mt < 2; ++mt) {
        int row = mt * 16 + c16;
        av[mt] = *(const bf16x8*)(Ab + (row >> 3) * 1024 + (row & 7) * 128 + (kb ^ ((row & 7) << 4)));
      }
      {
        int row = wave * 16 + c16;
        bv = *(const bf16x8*)(Bb + (row >> 3) * 1024 + (row & 7) * 128 + (kb ^ ((row & 7) << 4)));
      }
#pragma unroll
      for (int mt = 0; mt < 2; ++mt)
        acc[mt] = __builtin_amdgcn_mfma_f32_16x16x32_bf16(av[mt], bv, acc[mt], 0, 0, 0);
    }
    __syncthreads();
  }

  // epilogue: acc[mt][r] = S[bm*32 + mt*16 + lg*4 + r][g0 + wave*16 + c16] (minus b2)
  {
    int g = g0 + wave * 16 + c16;
    if (g < 4000) {
      float bb = b2[g];
      float theta = expf(log_theta[g]);
#pragma unroll
      for (int mt = 0; mt < 2; ++mt)
#pragma unroll
        for (int r = 0; r < 4; ++r) {
          int sample = bm * 32 + mt * 16 + lg * 4 + r;
          float s = acc[mt][r] + bb;
          float sig = 1.f / (1.f + expf(-s));
          float mu = (s > 20.f) ? s : log1pf(expf(s));
          float w = theta / (mu * (mu + theta) + 1e-6f);
          Cw[(size_t)sample * 4096 + g] = w * sig * sig;
        }
    } else {
#pragma unroll
      for (int mt = 0; mt < 2; ++mt)
#pragma unroll
        for (int r = 0; r < 4; ++r) {
          int sample = bm * 32 + mt * 16 + lg * 4 + r;
          Cw[(size_t)sample * 4096 + g] = 0.f;
        }
    }
  }
}

// ---------------- main GEMM: T = Astack @ W2T^T, fused Gram epilogue ----------------
// grid (64 M-tiles of 128 rows = 4 samples, 32 N-tiles of 128 genes), 256 threads
__global__ __launch_bounds__(256, 2) void k_gemm(const unsigned short* __restrict__ Astack,
                                                 const unsigned short* __restrict__ W2T,
                                                 const float* __restrict__ Cw,
                                                 float* __restrict__ Gram) {
  __shared__ __align__(16) char smem[65536];
  char* AbufB = smem;             // 2 * 16384
  char* BbufB = smem + 32768;     // 2 * 16384

  const int bm = blockIdx.x;
  const int g0 = blockIdx.y * 128;
  const int t = threadIdx.x;
  const int lane = t & 63;
  const int wave = t >> 6;
  const int wr = wave >> 1, wc = wave & 1;
  const int l8 = lane >> 3;
  const int kxor = (((lane & 7) ^ l8) << 3);
  const int c16 = lane & 15;
  const int lg = lane >> 4;

  f32x4 acc[4][4];
#pragma unroll
  for (int mt = 0; mt < 4; ++mt)
#pragma unroll
    for (int nt = 0; nt < 4; ++nt) acc[mt][nt] = (f32x4){0.f, 0.f, 0.f, 0.f};

  const size_t Abase = (size_t)bm * 128 * 512;

#define STAGE_G(buf, kt)                                                              \
  do {                                                                                \
    _Pragma("unroll") for (int qq = 0; qq < 4; ++qq) {                                \
      int q = wave * 4 + qq;                                                          \
      GLOAD16(Astack + Abase + (size_t)(q * 8 + l8) * 512 + (kt) * 64 + kxor,         \
              AbufB + (buf) * 16384 + q * 1024);                                      \
    }                                                                                 \
    _Pragma("unroll") for (int qq = 0; qq < 4; ++qq) {                                \
      int q = wave * 4 + qq;                                                          \
      GLOAD16(W2T + (size_t)(g0 + q * 8 + l8) * 512 + (kt) * 64 + kxor,               \
              BbufB + (buf) * 16384 + q * 1024);                                      \
    }                                                                                 \
  } while (0)

  STAGE_G(0, 0);
  __syncthreads();

  for (int kt = 0; kt < 8; ++kt) {
    int cur = kt & 1;
    if (kt < 7) STAGE_G(cur ^ 1, kt + 1);
    const char* Ab = AbufB + cur * 16384;
    const char* Bb = BbufB + cur * 16384;
#pragma unroll
    for (int ks = 0; ks < 2; ++ks) {
      int kb = ks * 64 + lg * 16;
      bf16x8 av[4], bv[4];
#pragma unroll
      for (int mt = 0; mt < 4; ++mt) {
        int row = wr * 64 + mt * 16 + c16;
        av[mt] = *(const bf16x8*)(Ab + (row >> 3) * 1024 + (row & 7) * 128 + (kb ^ ((row & 7) << 4)));
      }
#pragma unroll
      for (int nt = 0; nt < 4; ++nt) {
        int row = wc * 64 + nt * 16 + c16;
        bv[nt] = *(const bf16x8*)(Bb + (row >> 3) * 1024 + (row & 7) * 128 + (kb ^ ((row & 7) << 4)));
      }
#pragma unroll
      for (int mt = 0; mt < 4; ++mt)
#pragma unroll
        for (int nt = 0; nt < 4; ++nt)
          acc[mt][nt] = __builtin_amdgcn_mfma_f32_16x16x32_bf16(av[mt], bv[nt], acc[mt][nt], 0, 0, 0);
    }
    __syncthreads();
  }

  // ---- epilogue: T tile (bf16) -> LDS [128][136], c weights -> LDS ----
  unsigned short* T = (unsigned short*)smem;        // 128*136*2 = 34816 B
  float* c_lds = (float*)(smem + 34816);            // [4][128] = 2048 B

#pragma unroll
  for (int mt = 0; mt < 4; ++mt)
#pragma unroll
    for (int nt = 0; nt < 4; ++nt)
#pragma unroll
      for (int r = 0; r < 4; ++r) {
        int row = wr * 64 + mt * 16 + lg * 4 + r;
        int col = wc * 64 + nt * 16 + c16;
        T[row * 136 + col] = f2bf(acc[mt][nt][r]);
      }
#pragma unroll
  for (int k = 0; k < 2; ++k) {
    int e = t + k * 256;
    c_lds[e] = Cw[(size_t)(bm * 4 + (e >> 7)) * 4096 + g0 + (e & 127)];
  }
  __syncthreads();

  // ---- Gram via MFMA: wave w owns sample w; Gram32x32 += (c*T) @ T^T over 128 genes ----
  {
    const int s = wave;
    f32x4 gacc[2][2];
#pragma unroll
    for (int m2 = 0; m2 < 2; ++m2)
#pragma unroll
      for (int n2 = 0; n2 < 2; ++n2) gacc[m2][n2] = (f32x4){0.f, 0.f, 0.f, 0.f};

#pragma unroll
    for (int ch = 0; ch < 4; ++ch) {
      u16x8 raw[2];
      bf16x8 ap[2], bp[2];
      f32x4 cv0 = *(const f32x4*)(c_lds + s * 128 + ch * 32 + lg * 8);
      f32x4 cv1 = *(const f32x4*)(c_lds + s * 128 + ch * 32 + lg * 8 + 4);
#pragma unroll
      for (int m2 = 0; m2 < 2; ++m2) {
        int row = s * 32 + m2 * 16 + c16;
        raw[m2] = *(const u16x8*)((const char*)T + row * 272 + ch * 64 + lg * 16);
        u16x8 sc;
#pragma unroll
        for (int e = 0; e < 4; ++e) sc[e] = f2bf(bf2f(raw[m2][e]) * cv0[e]);
#pragma unroll
        for (int e = 0; e < 4; ++e) sc[4 + e] = f2bf(bf2f(raw[m2][4 + e]) * cv1[e]);
        ap[m2] = __builtin_bit_cast(bf16x8, sc);
        bp[m2] = __builtin_bit_cast(bf16x8, raw[m2]);
      }
#pragma unroll
      for (int m2 = 0; m2 < 2; ++m2)
#pragma unroll
        for (int n2 = 0; n2 < 2; ++n2)
          gacc[m2][n2] = __builtin_amdgcn_mfma_f32_16x16x32_bf16(ap[m2], bp[n2], gacc[m2][n2], 0, 0, 0);
    }

#pragma unroll
    for (int m2 = 0; m2 < 2; ++m2)
#pragma unroll
      for (int n2 = 0; n2 < 2; ++n2)
#pragma unroll
        for (int r = 0; r < 4; ++r) {
          int i = m2 * 16 + lg * 4 + r;
          int j = n2 * 16 + c16;
          atomicAdd(Gram + (size_t)(bm * 4 + s) * 1024 + i * 32 + j, gacc[m2][n2][r]);
        }
  }
}

// ---------------- loss reduce ----------------
__global__ __launch_bounds__(256) void k_loss(const float* __restrict__ Gram,
                                              float* __restrict__ out) {
  __shared__ float red[4];
  const int b = blockIdx.x, t = threadIdx.x;
  float local = 0.f;
#pragma unroll
  for (int k = 0; k < 4; ++k) {
    int e = t + k * 256;
    float d = Gram[(size_t)b * 1024 + e] - (((e >> 5) == (e & 31)) ? 1.f : 0.f);
    local += d * d;
  }
#pragma unroll
  for (int off = 32; off > 0; off >>= 1) local += __shfl_down(local, off);
  if ((t & 63) == 0) red[t >> 6] = local;
  __syncthreads();
  if (t == 0) {
    float s = red[0] + red[1] + red[2] + red[3];
    atomicAdd(out, s * (1.f / 256.f));
  }
}

extern "C" void kernel_launch(void* const* d_in, const int* in_sizes, int n_in,
                              void* d_out, int out_size, void* d_ws, size_t ws_size,
                              hipStream_t stream) {
  const float* z = (const float*)d_in[0];
  const float* W1 = (const float*)d_in[1];
  const float* b1 = (const float*)d_in[2];
  const float* W2 = (const float*)d_in[3];
  const float* b2 = (const float*)d_in[4];
  const float* lt = (const float*)d_in[5];

  char* ws = (char*)d_ws;
  unsigned short* W2T = (unsigned short*)ws;                   // 4,194,304
  unsigned short* Astack = (unsigned short*)(ws + 4194304);    // 8,388,608
  unsigned short* Hb = (unsigned short*)(ws + 12582912);       // 262,144
  float* Cw = (float*)(ws + 12976128);                         // 4,194,304
  float* Gram = (float*)(ws + 17170432);                       // 1,048,576

  hipMemsetAsync(Gram, 0, 256 * 1024 * 4, stream);
  hipMemsetAsync(d_out, 0, 4, stream);

  k_w2t<<<dim3(64, 8), 256, 0, stream>>>(W2, W2T);
  k_prep<<<256, 256, 0, stream>>>(z, W1, b1, Hb, Astack);
  k_s3<<<dim3(8, 64), 256, 0, stream>>>(Hb, W2T, b2, lt, Cw);
  k_gemm<<<dim3(64, 32), 256, 0, stream>>>(Astack, W2T, Cw, Gram);
  k_loss<<<256, 256, 0, stream>>>(Gram, (float*)d_out);
}